// Round 1
// baseline (289.953 us; speedup 1.0000x reference)
//
#include <hip/hip_runtime.h>
#include <hip/hip_bf16.h>

typedef __bf16 bf16x8 __attribute__((ext_vector_type(8)));
typedef float f32x4 __attribute__((ext_vector_type(4)));
typedef unsigned short u16x8 __attribute__((ext_vector_type(8)));

#define B_    16
#define CIN   128
#define H_    112
#define W_    112
#define COUT  256
#define HO    54
#define WO    54
#define EH    56
#define EW    56
#define M_PER_B (HO*WO)      // 2916
#define PPOS  136            // padded elems per spatial position in LDS patch (17*16B)

__device__ __forceinline__ unsigned short f2bf(float v) {
    __hip_bfloat16 h = __float2bfloat16(v);
    return __builtin_bit_cast(unsigned short, h);
}

// ---------------------------------------------------------------------------
// prep: per (b,h) row: channel-sum S; for even h, even w: bf16 even-subsample E
// (channel-LAST layout E[b][i][j][c]) via LDS transpose. Tail blocks repack W
// into Wb[tap][o][c] bf16 (GEMM B-matrix layout).
// ---------------------------------------------------------------------------
__global__ __launch_bounds__(128) void prep_kernel(
    const float* __restrict__ in, const float* __restrict__ w,
    unsigned short* __restrict__ E, float* __restrict__ S,
    unsigned short* __restrict__ Wb)
{
    const int blk = blockIdx.x;
    const int tid = threadIdx.x;
    if (blk < B_ * H_) {
        __shared__ unsigned short lds[CIN][EW + 2];  // +2 pad: conflict-free transpose read
        const int b = blk / H_, h = blk % H_;
        const bool evenh = (h & 1) == 0;
        float ssum = 0.f;
        const float* rowbase = in + ((size_t)(b * CIN) * H_ + h) * W_;
        for (int c = 0; c < CIN; ++c) {
            float v = (tid < W_) ? rowbase[(size_t)c * H_ * W_ + tid] : 0.f;
            ssum += v;
            if (evenh && tid < W_ && !(tid & 1))
                lds[c][tid >> 1] = f2bf(v);
        }
        if (tid < W_) S[(b * H_ + h) * W_ + tid] = ssum;
        if (evenh) {
            __syncthreads();
            const int i = h >> 1;
            unsigned short* Erow = E + ((size_t)(b * EH + i) * EW) * CIN;
            for (int f = tid; f < EW * CIN; f += 128) {
                int j = f >> 7, c = f & 127;
                Erow[f] = lds[c][j];
            }
        }
    } else {
        // W repack: Wb[(t*COUT + o)*CIN + c] = bf16(w[(o*CIN + c)*9 + ki*3 + kj])
        const int gt = (blk - B_ * H_) * 128 + tid;      // 0..9215
        for (int idx = gt; idx < 9 * COUT * CIN; idx += 72 * 128) {
            int t   = idx / (COUT * CIN);
            int rem = idx % (COUT * CIN);                // o*CIN + c
            int ki = t / 3, kj = t % 3;
            Wb[idx] = f2bf(w[(size_t)rem * 9 + ki * 3 + kj]);
        }
    }
}

// ---------------------------------------------------------------------------
// T[b,y,x] = 0.1 * (sum of 5x5 S patch - sum of even-even 3x3 subgrid)
// ---------------------------------------------------------------------------
__global__ __launch_bounds__(256) void t_kernel(
    const float* __restrict__ S, float* __restrict__ T)
{
    int idx = blockIdx.x * 256 + threadIdx.x;
    if (idx >= B_ * M_PER_B) return;
    int b = idx / M_PER_B, m = idx % M_PER_B;
    int y = m / WO, x = m % WO;
    const float* Sp = S + ((size_t)(b * H_) + 2 * y) * W_ + 2 * x;
    float s25 = 0.f, s9 = 0.f;
    #pragma unroll
    for (int i = 0; i < 5; ++i) {
        #pragma unroll
        for (int j = 0; j < 5; ++j) {
            float v = Sp[i * W_ + j];
            s25 += v;
            if (!(i & 1) && !(j & 1)) s9 += v;
        }
    }
    T[idx] = 0.1f * (s25 - s9);
}

// ---------------------------------------------------------------------------
// conv: block = (b, 2 output rows). M=108 (7 x 16 subtiles, last padded),
// N=256. 8 waves = 2 m-groups (subs 0..3 / 3..6, sub 3 duplicated benignly)
// x 4 n-groups of 64. Patch (4 rows x 56 pos x 128c bf16) staged to LDS once;
// K-loop = 9 taps x 4 c-chunks, no barriers. B-frags straight from L2.
// ---------------------------------------------------------------------------
__global__ __launch_bounds__(512) void conv_kernel(
    const unsigned short* __restrict__ E, const unsigned short* __restrict__ Wb,
    const float* __restrict__ T, const float* __restrict__ bias1,
    float* __restrict__ out)
{
    __shared__ unsigned short patch[4 * EW * PPOS];   // 60928 B

    const int tid = threadIdx.x;
    const int b  = blockIdx.y;
    const int y0 = blockIdx.x * 2;

    // stage: rows y0..y0+3 of E for this b are one contiguous 57344 B span
    const unsigned short* Eg = E + ((size_t)(b * EH + y0) * EW) * CIN;
    #pragma unroll
    for (int it = 0; it < 7; ++it) {
        int ch = tid + it * 512;          // 0..3583 chunks of 16B
        int pos = ch >> 4, cs = ch & 15;
        u16x8 v = *reinterpret_cast<const u16x8*>(Eg + (size_t)ch * 8);
        *reinterpret_cast<u16x8*>(&patch[pos * PPOS + cs * 8]) = v;
    }
    __syncthreads();

    const int lane = tid & 63;
    const int wid  = tid >> 6;        // 0..7
    const int wm   = wid >> 2;        // 0..1  (m-group)
    const int wn   = wid & 3;         // 0..3  (n-group of 64)
    const int lm   = lane & 15;
    const int kq   = lane >> 4;

    int aoff[4];
    #pragma unroll
    for (int mi = 0; mi < 4; ++mi) {
        int s = wm * 3 + mi;
        int m = s * 16 + lm; if (m > 107) m = 107;   // pad lanes read row 107
        int ty = m / WO, tx = m % WO;
        aoff[mi] = (ty * EW + tx) * PPOS + kq * 8;
    }
    int bcol[4];
    #pragma unroll
    for (int ni = 0; ni < 4; ++ni)
        bcol[ni] = (wn * 64 + ni * 16 + lm) * CIN + kq * 8;

    f32x4 acc[4][4];
    #pragma unroll
    for (int mi = 0; mi < 4; ++mi)
        #pragma unroll
        for (int ni = 0; ni < 4; ++ni)
            acc[mi][ni] = (f32x4){0.f, 0.f, 0.f, 0.f};

    #pragma unroll
    for (int t = 0; t < 9; ++t) {
        const int tapoff = ((t / 3) * EW + (t % 3)) * PPOS;
        const unsigned short* wt = Wb + (size_t)t * (COUT * CIN);
        #pragma unroll
        for (int c0 = 0; c0 < 128; c0 += 32) {
            bf16x8 a[4], bb[4];
            #pragma unroll
            for (int mi = 0; mi < 4; ++mi)
                a[mi] = __builtin_bit_cast(bf16x8,
                    *reinterpret_cast<const u16x8*>(&patch[aoff[mi] + tapoff + c0]));
            #pragma unroll
            for (int ni = 0; ni < 4; ++ni)
                bb[ni] = __builtin_bit_cast(bf16x8,
                    *reinterpret_cast<const u16x8*>(wt + bcol[ni] + c0));
            #pragma unroll
            for (int mi = 0; mi < 4; ++mi)
                #pragma unroll
                for (int ni = 0; ni < 4; ++ni)
                    acc[mi][ni] = __builtin_amdgcn_mfma_f32_16x16x32_bf16(
                        a[mi], bb[ni], acc[mi][ni], 0, 0, 0);
        }
    }

    // epilogue: out[b][o][m] = acc + bias1[o] * T[b][m]; m-contiguous float4
    const int mglob0 = y0 * WO;
    #pragma unroll
    for (int mi = 0; mi < 4; ++mi) {
        int s  = wm * 3 + mi;
        int mb = s * 16 + kq * 4;
        if (mb >= 108) continue;      // padded tail of subtile 6
        f32x4 tv = *reinterpret_cast<const f32x4*>(T + (size_t)b * M_PER_B + mglob0 + mb);
        #pragma unroll
        for (int ni = 0; ni < 4; ++ni) {
            int o = wn * 64 + ni * 16 + lm;
            float bo = bias1[o];
            f32x4 r;
            r[0] = acc[mi][ni][0] + bo * tv[0];
            r[1] = acc[mi][ni][1] + bo * tv[1];
            r[2] = acc[mi][ni][2] + bo * tv[2];
            r[3] = acc[mi][ni][3] + bo * tv[3];
            float* op = out + ((size_t)(b * COUT + o)) * M_PER_B + mglob0 + mb;
            *reinterpret_cast<f32x4*>(op) = r;
        }
    }
}

// ---------------------------------------------------------------------------
extern "C" void kernel_launch(void* const* d_in, const int* in_sizes, int n_in,
                              void* d_out, int out_size, void* d_ws, size_t ws_size,
                              hipStream_t stream)
{
    const float* in = (const float*)d_in[0];
    const float* w  = (const float*)d_in[1];
    const float* b1 = (const float*)d_in[2];
    float* out = (float*)d_out;

    char* ws = (char*)d_ws;
    unsigned short* E  = (unsigned short*)ws;                  // 16*56*56*128*2 = 12,845,056
    size_t off = 12845056;
    float* S = (float*)(ws + off);  off += 802816;             // 16*112*112*4
    float* T = (float*)(ws + off);  off += 186624;             // 16*2916*4
    unsigned short* Wb = (unsigned short*)(ws + off);          // 9*256*128*2 = 589,824

    prep_kernel<<<dim3(B_ * H_ + 72), 128, 0, stream>>>(in, w, E, S, Wb);
    t_kernel<<<dim3((B_ * M_PER_B + 255) / 256), 256, 0, stream>>>(S, T);
    conv_kernel<<<dim3(HO / 2, B_), 512, 0, stream>>>(E, Wb, T, b1, out);
}